// Round 5
// baseline (551.588 us; speedup 1.0000x reference)
//
#include <hip/hip_runtime.h>
#include <hip/hip_bf16.h>

// LabelContextAttentionBlock on MI355X (gfx950).
// Pipeline: kd_prep (fold BN into fp16 weights) -> ka_ctx (context GEMM, fp32,
// split-K partials) -> kb_kv (reduce + key/value convs, fp32, fp16 outputs in
// MFMA-B-fragment-friendly layouts) -> kc_qattn (fp16-MFMA query convs fused
// with attention: sim -> softmax -> PV, fp32 accum everywhere).
//
// R1 post-mortem: bf16 storage (rel 4e-3) on q2/k2 gave logit err ~0.4 ->
// softmax tie reshuffle -> absmax 106. fp16 (rel 5e-4) brings logit err to
// ~0.04 -> out err ~12 < 21.76 threshold. fp16 MFMA rate == bf16 rate.
// R2/R3/R4: broker timeouts, never ran — resubmitting unchanged.
//
// Sizes: B=8, C=512, H=W=96 (HW=9216), O=256, L=19. All inputs fp32.

typedef _Float16 f16;
typedef __attribute__((ext_vector_type(8))) _Float16 f16x8;
typedef __attribute__((ext_vector_type(4))) float f32x4;

// ---------------------------------------------------------------------------
// Workspace layout (bytes):
#define OFF_PART   0            // [8 s][8 b][512 c][19 l] f32 = 2,490,368
#define OFF_W1F    2490368      // [256 o][512 k] f16 = 262,144
#define OFF_W2F    2752512      // [256 o][256 k] f16 = 131,072
#define OFF_T1     2883584      // [256] f32
#define OFF_T2     2884608      // [256] f32
#define OFF_KEYT   2885632      // [8 b][32 l][256 o] f16 (l>=19 zero) = 131,072
#define OFF_VALT   3016704      // [8 b][256 o][32 l] f16 (l>=19 zero) = 131,072
// total 3,147,776 bytes

// ---------------------------------------------------------------------------
// kd_prep: fold BN scale into query-path weights, convert to fp16.
// bn fold: y*s + t with s = g/sqrt(v+eps), t = beta - mean*s.
__global__ __launch_bounds__(256)
void kd_prep(const float* __restrict__ Wq1, const float* __restrict__ bnq1,
             const float* __restrict__ Wq2, const float* __restrict__ bnq2,
             f16* __restrict__ w1f, f16* __restrict__ w2f,
             float* __restrict__ t1, float* __restrict__ t2)
{
  const int bid = blockIdx.x;
  const int t = threadIdx.x;
  if (bid < 256) {
    const int o = bid;
    float gg = bnq1[o], be = bnq1[256 + o], mm = bnq1[512 + o], vv = bnq1[768 + o];
    float sc = gg / sqrtf(vv + 1e-5f);
    if (t == 0) t1[o] = be - mm * sc;
    for (int k = t; k < 512; k += 256)
      w1f[(size_t)o * 512 + k] = (f16)(Wq1[(size_t)o * 512 + k] * sc);
  } else {
    const int o = bid - 256;
    float gg = bnq2[o], be = bnq2[256 + o], mm = bnq2[512 + o], vv = bnq2[768 + o];
    float sc = gg / sqrtf(vv + 1e-5f);
    if (t == 0) t2[o] = be - mm * sc;
    w2f[(size_t)o * 256 + t] = (f16)(Wq2[(size_t)o * 256 + t] * sc);
  }
}

// ---------------------------------------------------------------------------
// ka_ctx: context[b,c,l] = sum_h aux[b,l,h] * sf[b,c,h]  (fp32, split-K=8)
// Block = (ctile 64, b, kslice). Thread (cx = tid>>2, lx = tid&3) owns
// channel c0+cx and l in {lx, lx+4, ...} -> no cross-thread reduction.
__global__ __launch_bounds__(256)
void ka_ctx(const float* __restrict__ sf, const float* __restrict__ aux,
            float* __restrict__ part)
{
  __shared__ float sf_lds[64 * 72];   // pitch 72
  __shared__ float aux_lds[19 * 68];  // pitch 68
  const int tid = threadIdx.x;
  const int c0 = blockIdx.x * 64;
  const int b = blockIdx.y;
  const int s = blockIdx.z;
  const int h0 = s * 1152;
  const int cx = tid >> 2;
  const int lx = tid & 3;
  const float* sfb = sf + (size_t)b * 512 * 9216;
  const float* auxb = aux + (size_t)b * 19 * 9216;

  f32x4 z = {0.f, 0.f, 0.f, 0.f};
  f32x4 a4[5];
#pragma unroll
  for (int i = 0; i < 5; ++i) a4[i] = z;

  for (int ch = 0; ch < 18; ++ch) {
    const int hb = h0 + ch * 64;
#pragma unroll
    for (int i = 0; i < 4; ++i) {
      int fl = tid + i * 256;          // 1024 float4s = 64c x 64h
      int row = fl >> 4, h4 = fl & 15;
      *(f32x4*)&sf_lds[row * 72 + h4 * 4] =
          *(const f32x4*)(sfb + (size_t)(c0 + row) * 9216 + hb + h4 * 4);
    }
#pragma unroll
    for (int i = 0; i < 5; ++i) {
      int fl = tid + i * 256;          // 1216 floats = 19l x 64h
      if (fl < 1216) {
        int row = fl >> 6, kk = fl & 63;
        aux_lds[row * 68 + kk] = auxb[(size_t)row * 9216 + hb + kk];
      }
    }
    __syncthreads();
#pragma unroll 4
    for (int k4 = 0; k4 < 16; ++k4) {
      f32x4 sv = *(const f32x4*)&sf_lds[cx * 72 + k4 * 4];
#pragma unroll
      for (int i = 0; i < 5; ++i) {
        int l = lx + 4 * i;
        if (l < 19) {
          f32x4 av = *(const f32x4*)&aux_lds[l * 68 + k4 * 4];
          a4[i] += sv * av;
        }
      }
    }
    __syncthreads();
  }
#pragma unroll
  for (int i = 0; i < 5; ++i) {
    int l = lx + 4 * i;
    if (l < 19) {
      float v = a4[i][0] + a4[i][1] + a4[i][2] + a4[i][3];
      part[(((size_t)s * 8 + b) * 512 + c0 + cx) * 19 + l] = v;
    }
  }
}

// ---------------------------------------------------------------------------
// kb_kv: reduce split-K partials -> context; key/value 1x1 convs (fp32);
// write keyT[b][32 l][256 o] and valT[b][256 o][32 l] f16, zero-padded l>=19.
__global__ __launch_bounds__(256)
void kb_kv(const float* __restrict__ part,
           const float* __restrict__ Wk1, const float* __restrict__ bnk1,
           const float* __restrict__ Wk2, const float* __restrict__ bnk2,
           const float* __restrict__ Wv, const float* __restrict__ bnv,
           f16* __restrict__ keyT, f16* __restrict__ valT)
{
  const int l = blockIdx.x;   // 0..31
  const int b = blockIdx.y;
  const int t = threadIdx.x;  // 0..255 (= output channel o)
  f16* keyrow = keyT + ((size_t)b * 32 + l) * 256;
  f16* valb = valT + (size_t)b * 256 * 32;
  if (l >= 19) {  // zero padding rows/cols (whole block returns together)
    keyrow[t] = (f16)0.f;
    valb[(size_t)t * 32 + l] = (f16)0.f;
    return;
  }
  __shared__ float ctx[512];
  __shared__ float k1[256];
  for (int cc = t; cc < 512; cc += 256) {
    float acc = 0.f;
#pragma unroll
    for (int s = 0; s < 8; ++s)
      acc += part[(((size_t)s * 8 + b) * 512 + cc) * 19 + l];
    ctx[cc] = acc;
  }
  __syncthreads();
  {
    const float* w = Wk1 + (size_t)t * 512;
    f32x4 d4 = {0.f, 0.f, 0.f, 0.f};
    for (int k = 0; k < 512; k += 4)
      d4 += (*(const f32x4*)(w + k)) * (*(const f32x4*)&ctx[k]);
    float d = d4[0] + d4[1] + d4[2] + d4[3];
    float gg = bnk1[t], be = bnk1[256 + t], mm = bnk1[512 + t], vv = bnk1[768 + t];
    float sc = gg / sqrtf(vv + 1e-5f);
    k1[t] = fmaxf(d * sc + (be - mm * sc), 0.f);
  }
  __syncthreads();
  {
    const float* w = Wk2 + (size_t)t * 256;
    f32x4 d4 = {0.f, 0.f, 0.f, 0.f};
    for (int k = 0; k < 256; k += 4)
      d4 += (*(const f32x4*)(w + k)) * (*(const f32x4*)&k1[k]);
    float d = d4[0] + d4[1] + d4[2] + d4[3];
    float gg = bnk2[t], be = bnk2[256 + t], mm = bnk2[512 + t], vv = bnk2[768 + t];
    float sc = gg / sqrtf(vv + 1e-5f);
    keyrow[t] = (f16)fmaxf(d * sc + (be - mm * sc), 0.f);
  }
  {
    const float* w = Wv + (size_t)t * 512;
    f32x4 d4 = {0.f, 0.f, 0.f, 0.f};
    for (int k = 0; k < 512; k += 4)
      d4 += (*(const f32x4*)(w + k)) * (*(const f32x4*)&ctx[k]);
    float d = d4[0] + d4[1] + d4[2] + d4[3];
    float gg = bnv[t], be = bnv[256 + t], mm = bnv[512 + t], vv = bnv[768 + t];
    float sc = gg / sqrtf(vv + 1e-5f);
    valb[(size_t)t * 32 + l] = (f16)fmaxf(d * sc + (be - mm * sc), 0.f);
  }
}

// ---------------------------------------------------------------------------
// kc_qattn: per block = 128 pixels x full O=256. 4 waves (2n x 2o).
// GEMM1 (K=512): D[n][o] = x^T @ (s1.Wq1)^T; x staged in LDS transposed
// ([n][k] f16, XOR-swizzled chunks); W frags straight from L2.
// GEMM2 (K=256): q1 from LDS [n][264], W2 from L2. q2 overwrites q1 in LDS.
// sim (K=256, L padded to 32) -> shfl softmax -> p in LDS -> PV MFMA -> store.
// MFMA frag maps (gfx950 16x16x32 f16): A: row=lane&15, k=8*(lane>>4)+e;
// B: col=lane&15, k=8*(lane>>4)+e; D: col=lane&15, row=4*(lane>>4)+reg.
__global__ __launch_bounds__(256, 2)
void kc_qattn(const float* __restrict__ x, const f16* __restrict__ w1f,
              const f16* __restrict__ w2f, const float* __restrict__ t1,
              const float* __restrict__ t2, const f16* __restrict__ keyT,
              const f16* __restrict__ valT, float* __restrict__ out)
{
  __shared__ f16 q_lds[128 * 264];  // q1 then q2, [n][o] f16, pitch 264
  __shared__ f16 xp_lds[128 * 40];  // x chunk [n][k] swizzled; later p [n][l]

  const int tid = threadIdx.x;
  const int lane = tid & 63;
  const int wave = tid >> 6;
  const int c = lane & 15;   // frag col lane
  const int g = lane >> 4;   // frag k/row group
  const int b = blockIdx.y;
  const int n0 = blockIdx.x * 128;
  const int wn = wave & 1;   // n half (64 rows)
  const int wo = wave >> 1;  // o half (128 cols)

  const float* xb = x + (size_t)b * 512 * 9216;
  const f32x4 zero4 = {0.f, 0.f, 0.f, 0.f};

  f32x4 acc[32];
#pragma unroll
  for (int i = 0; i < 32; ++i) acc[i] = zero4;

  // ---- GEMM1: q1[128 n][256 o], K = 512 in chunks of 32
  for (int kc = 0; kc < 16; ++kc) {
    // stage x chunk (32 k x 128 n f32) -> xp_lds[n][k] f16 (swizzled)
#pragma unroll
    for (int i = 0; i < 4; ++i) {
      int fl = tid + i * 256;       // 0..1023 float4s
      int row = fl >> 5;            // k 0..31
      int col4 = fl & 31;           // n/4
      f32x4 v = *(const f32x4*)(xb + (size_t)(kc * 32 + row) * 9216 + n0 + col4 * 4);
      int base = (col4 * 4) * 40 + (((row >> 3) ^ (col4 & 3)) << 3) + (row & 7);
      xp_lds[base] = (f16)v[0];
      xp_lds[base + 40] = (f16)v[1];
      xp_lds[base + 80] = (f16)v[2];
      xp_lds[base + 120] = (f16)v[3];
    }
    __syncthreads();
    f16x8 af[4], bw[8];
#pragma unroll
    for (int m = 0; m < 4; ++m) {
      int n_ = wn * 64 + m * 16 + c;
      af[m] = *(const f16x8*)&xp_lds[n_ * 40 + ((g ^ ((n_ >> 2) & 3)) << 3)];
    }
#pragma unroll
    for (int j = 0; j < 8; ++j) {
      int o = wo * 128 + j * 16 + c;
      bw[j] = *(const f16x8*)(w1f + (size_t)o * 512 + kc * 32 + g * 8);
    }
#pragma unroll
    for (int m = 0; m < 4; ++m)
#pragma unroll
      for (int j = 0; j < 8; ++j)
        acc[m * 8 + j] = __builtin_amdgcn_mfma_f32_16x16x32_f16(af[m], bw[j], acc[m * 8 + j], 0, 0, 0);
    __syncthreads();
  }

  // epilogue1: q1 = relu(acc + t1[o]) -> q_lds f16
#pragma unroll
  for (int j = 0; j < 8; ++j) {
    int o = wo * 128 + j * 16 + c;
    float tb = t1[o];
#pragma unroll
    for (int m = 0; m < 4; ++m) {
      int nb = wn * 64 + m * 16 + g * 4;
#pragma unroll
      for (int r = 0; r < 4; ++r) {
        float v = fmaxf(acc[m * 8 + j][r] + tb, 0.f);
        q_lds[(nb + r) * 264 + o] = (f16)v;
      }
    }
  }
  __syncthreads();

  // ---- GEMM2: q2[128 n][256 o2], K = 256 in chunks of 32
#pragma unroll
  for (int i = 0; i < 32; ++i) acc[i] = zero4;
  for (int kc = 0; kc < 8; ++kc) {
    f16x8 aq[4], bw2[8];
#pragma unroll
    for (int m = 0; m < 4; ++m) {
      int n_ = wn * 64 + m * 16 + c;
      aq[m] = *(const f16x8*)&q_lds[n_ * 264 + kc * 32 + g * 8];
    }
#pragma unroll
    for (int j = 0; j < 8; ++j) {
      int o = wo * 128 + j * 16 + c;
      bw2[j] = *(const f16x8*)(w2f + (size_t)o * 256 + kc * 32 + g * 8);
    }
#pragma unroll
    for (int m = 0; m < 4; ++m)
#pragma unroll
      for (int j = 0; j < 8; ++j)
        acc[m * 8 + j] = __builtin_amdgcn_mfma_f32_16x16x32_f16(aq[m], bw2[j], acc[m * 8 + j], 0, 0, 0);
  }
  __syncthreads();  // all q1 reads complete before overwrite

  // epilogue2: q2 = relu(acc + t2[o]) -> q_lds (in place)
#pragma unroll
  for (int j = 0; j < 8; ++j) {
    int o = wo * 128 + j * 16 + c;
    float tb = t2[o];
#pragma unroll
    for (int m = 0; m < 4; ++m) {
      int nb = wn * 64 + m * 16 + g * 4;
#pragma unroll
      for (int r = 0; r < 4; ++r) {
        float v = fmaxf(acc[m * 8 + j][r] + tb, 0.f);
        q_lds[(nb + r) * 264 + o] = (f16)v;
      }
    }
  }
  __syncthreads();

  // ---- sim[128 n][32 l] = q2 @ keyT, K = 256 (wave = 32 n x 32 l)
  f32x4 accs[4];
#pragma unroll
  for (int i = 0; i < 4; ++i) accs[i] = zero4;
  const f16* keyb = keyT + (size_t)b * 32 * 256;
  for (int kc = 0; kc < 8; ++kc) {
    f16x8 aq[2], bk[2];
#pragma unroll
    for (int m2 = 0; m2 < 2; ++m2) {
      int n_ = wave * 32 + m2 * 16 + c;
      aq[m2] = *(const f16x8*)&q_lds[n_ * 264 + kc * 32 + g * 8];
    }
#pragma unroll
    for (int lf = 0; lf < 2; ++lf)
      bk[lf] = *(const f16x8*)(keyb + (size_t)(lf * 16 + c) * 256 + kc * 32 + g * 8);
#pragma unroll
    for (int m2 = 0; m2 < 2; ++m2)
#pragma unroll
      for (int lf = 0; lf < 2; ++lf)
        accs[m2 * 2 + lf] = __builtin_amdgcn_mfma_f32_16x16x32_f16(aq[m2], bk[lf], accs[m2 * 2 + lf], 0, 0, 0);
  }

  // softmax over l (19 valid) per row; p -> xp_lds[n][40] f16 (cols 0..31)
  const float kscale = 0.0625f * 1.44269504088896f;  // (1/sqrt(256)) * log2(e)
#pragma unroll
  for (int m2 = 0; m2 < 2; ++m2) {
#pragma unroll
    for (int r = 0; r < 4; ++r) {
      float v0 = accs[m2 * 2 + 0][r];           // l = c
      float v1 = accs[m2 * 2 + 1][r];           // l = 16 + c (valid c<3)
      float v1m = (c < 3) ? v1 : -3.0e38f;
      float mx = fmaxf(v0, v1m);
      mx = fmaxf(mx, __shfl_xor(mx, 1));
      mx = fmaxf(mx, __shfl_xor(mx, 2));
      mx = fmaxf(mx, __shfl_xor(mx, 4));
      mx = fmaxf(mx, __shfl_xor(mx, 8));
      float p0 = exp2f((v0 - mx) * kscale);
      float p1 = (c < 3) ? exp2f((v1 - mx) * kscale) : 0.f;
      float sm = p0 + p1;
      sm += __shfl_xor(sm, 1);
      sm += __shfl_xor(sm, 2);
      sm += __shfl_xor(sm, 4);
      sm += __shfl_xor(sm, 8);
      float rs = 1.0f / sm;
      int n_ = wave * 32 + m2 * 16 + g * 4 + r;
      xp_lds[n_ * 40 + c] = (f16)(p0 * rs);
      xp_lds[n_ * 40 + 16 + c] = (f16)(p1 * rs);  // c>=3 writes zeros (pad)
    }
  }
  __syncthreads();

  // ---- out[n][o] = p @ valT, K = 32 (wave = 32 n x 256 o)
#pragma unroll
  for (int i = 0; i < 32; ++i) acc[i] = zero4;
  const f16* valb = valT + (size_t)b * 256 * 32;
  f16x8 ap[2];
#pragma unroll
  for (int m2 = 0; m2 < 2; ++m2) {
    int n_ = wave * 32 + m2 * 16 + c;
    ap[m2] = *(const f16x8*)&xp_lds[n_ * 40 + g * 8];
  }
#pragma unroll
  for (int j = 0; j < 16; ++j) {
    f16x8 bv = *(const f16x8*)(valb + (size_t)(j * 16 + c) * 32 + g * 8);
#pragma unroll
    for (int m2 = 0; m2 < 2; ++m2)
      acc[m2 * 16 + j] = __builtin_amdgcn_mfma_f32_16x16x32_f16(ap[m2], bv, acc[m2 * 16 + j], 0, 0, 0);
  }
  float* ob = out + (size_t)b * 256 * 9216;
#pragma unroll
  for (int j = 0; j < 16; ++j) {
    int o = j * 16 + c;
#pragma unroll
    for (int m2 = 0; m2 < 2; ++m2) {
      int n_ = wave * 32 + m2 * 16 + g * 4;
      *(f32x4*)(ob + (size_t)o * 9216 + n0 + n_) = acc[m2 * 16 + j];
    }
  }
}

// ---------------------------------------------------------------------------
extern "C" void kernel_launch(void* const* d_in, const int* in_sizes, int n_in,
                              void* d_out, int out_size, void* d_ws, size_t ws_size,
                              hipStream_t stream) {
  (void)in_sizes; (void)n_in; (void)out_size; (void)ws_size;
  const float* tgt  = (const float*)d_in[0];
  const float* src  = (const float*)d_in[1];
  const float* aux  = (const float*)d_in[2];
  // d_in[3] (source_aux_prob) unused by the reference
  const float* Wq1  = (const float*)d_in[4];
  const float* bnq1 = (const float*)d_in[5];
  const float* Wq2  = (const float*)d_in[6];
  const float* bnq2 = (const float*)d_in[7];
  const float* Wk1  = (const float*)d_in[8];
  const float* bnk1 = (const float*)d_in[9];
  const float* Wk2  = (const float*)d_in[10];
  const float* bnk2 = (const float*)d_in[11];
  const float* Wv   = (const float*)d_in[12];
  const float* bnv  = (const float*)d_in[13];
  float* out = (float*)d_out;
  char* ws = (char*)d_ws;

  float* part = (float*)(ws + OFF_PART);
  f16* w1f  = (f16*)(ws + OFF_W1F);
  f16* w2f  = (f16*)(ws + OFF_W2F);
  float* t1 = (float*)(ws + OFF_T1);
  float* t2 = (float*)(ws + OFF_T2);
  f16* keyT = (f16*)(ws + OFF_KEYT);
  f16* valT = (f16*)(ws + OFF_VALT);

  hipLaunchKernelGGL(kd_prep, dim3(512), dim3(256), 0, stream,
                     Wq1, bnq1, Wq2, bnq2, w1f, w2f, t1, t2);
  hipLaunchKernelGGL(ka_ctx, dim3(8, 8, 8), dim3(256), 0, stream, src, aux, part);
  hipLaunchKernelGGL(kb_kv, dim3(32, 8), dim3(256), 0, stream,
                     part, Wk1, bnk1, Wk2, bnk2, Wv, bnv, keyT, valT);
  hipLaunchKernelGGL(kc_qattn, dim3(72, 8), dim3(256), 0, stream,
                     tgt, w1f, w2f, t1, t2, keyT, valT, out);
}